// Round 1
// baseline (304.543 us; speedup 1.0000x reference)
//
#include <hip/hip_runtime.h>

#define Bn 8
#define Cn 128
#define Hn 64
#define Wn 64
#define HWn 4096
#define KK 9

// ---------------------------------------------------------------------------
// Kernel 1: per-(b,c) plane: depthwise 3x3 (recomputed, not stored) + sums of
// Xs and Y2 for the global-average-pool of the context branch.
// ---------------------------------------------------------------------------
__global__ __launch_bounds__(256) void k_pool(
    const float* __restrict__ X2, const float* __restrict__ Y2,
    const float* __restrict__ sw, float* __restrict__ mXs,
    float* __restrict__ mY2)
{
    int bc = blockIdx.x;              // b*128 + c
    int c = bc & (Cn - 1);
    const float* xp = X2 + (size_t)bc * HWn;
    const float* yp = Y2 + (size_t)bc * HWn;
    float wk[9];
#pragma unroll
    for (int i = 0; i < 9; i++) wk[i] = sw[c * 9 + i];

    float sx = 0.f, sy = 0.f;
    for (int idx = threadIdx.x; idx < HWn; idx += 256) {
        int h = idx >> 6, w = idx & 63;
        float acc = 0.f;
#pragma unroll
        for (int i = 0; i < 3; i++) {
            int hh = h + i - 1;
            if (hh < 0 || hh >= Hn) continue;
#pragma unroll
            for (int j = 0; j < 3; j++) {
                int ww = w + j - 1;
                if (ww < 0 || ww >= Wn) continue;
                acc += xp[hh * Wn + ww] * wk[i * 3 + j];
            }
        }
        sx += acc;
        sy += yp[idx];
    }
    __shared__ float r0[256], r1[256];
    int t = threadIdx.x;
    r0[t] = sx; r1[t] = sy;
    __syncthreads();
    for (int s = 128; s > 0; s >>= 1) {
        if (t < s) { r0[t] += r0[t + s]; r1[t] += r1[t + s]; }
        __syncthreads();
    }
    if (t == 0) {
        mXs[bc] = r0[0] * (1.f / HWn);
        mY2[bc] = r1[0] * (1.f / HWn);
    }
}

// ---------------------------------------------------------------------------
// Kernel 2: tiny context MLP per batch: mfc(256) -> w1 -> ctx1(64) -> w2+relu
// -> ctx2(64) -> w3 -> channel_filter (128*9)
// ---------------------------------------------------------------------------
__global__ __launch_bounds__(256) void k_ctx(
    const float* __restrict__ mXs, const float* __restrict__ mY2,
    const float* __restrict__ w1, const float* __restrict__ w2,
    const float* __restrict__ w3, float* __restrict__ cf)
{
    int b = blockIdx.x;
    __shared__ float mfc[256], c1[64], c2[64];
    int t = threadIdx.x;
    mfc[t] = (t < Cn) ? mXs[b * Cn + t] : mY2[b * Cn + t - Cn];
    __syncthreads();
    if (t < 64) {
        float a = 0.f;
        for (int c = 0; c < 256; c++) a += w1[t * 256 + c] * mfc[c];
        c1[t] = a;
    }
    __syncthreads();
    if (t < 64) {
        float a = 0.f;
        for (int c = 0; c < 64; c++) a += w2[t * 64 + c] * c1[c];
        c2[t] = fmaxf(a, 0.f);
    }
    __syncthreads();
    for (int j = t; j < Cn * KK; j += 256) {
        float a = 0.f;
        for (int c = 0; c < 64; c++) a += w3[j * 64 + c] * c2[c];
        cf[b * Cn * KK + j] = a;
    }
}

// ---------------------------------------------------------------------------
// Kernel 3: one block per (b, h) row of 64 pixels.
//  Phase 0: recompute Xs row into LDS, load Y2 row into LDS (in sDyn).
//  Phase A: spatial filter sf[9][64] = ws @ Fc.
//  Phase B: dynamic_out row -> sDyn (overwrites Y2 copy).
//  Phase C: fusion conv out = wf @ [Xs ; dyn], wave-uniform scalar wf loads.
// ---------------------------------------------------------------------------
__global__ __launch_bounds__(256, 2) void k_main(
    const float* __restrict__ X2, const float* __restrict__ Y2,
    const float* __restrict__ sw, const float* __restrict__ wsp,
    const float* __restrict__ wf, const float* __restrict__ cf,
    float* __restrict__ out)
{
    __shared__ float sXs[Cn][Wn];    // 32 KB
    __shared__ float sDyn[Cn][Wn];   // 32 KB (Y2 row, then dynamic_out row)
    __shared__ float sSf[KK][Wn];    // 2.3 KB
    __shared__ float sCf[Cn * KK];   // 4.6 KB

    int bh = blockIdx.x;
    int b = bh >> 6, h = bh & 63;
    size_t base = (size_t)b * Cn * HWn + (size_t)h * Wn;

    // Phase 0: depthwise row + Y2 row into LDS
    for (int idx = threadIdx.x; idx < Cn * Wn; idx += 256) {
        int c = idx >> 6, w = idx & 63;
        const float* xrow = X2 + (size_t)(b * Cn + c) * HWn;
        const float* swc = sw + c * 9;
        float a = 0.f;
#pragma unroll
        for (int i = 0; i < 3; i++) {
            int hh = h + i - 1;
            if (hh < 0 || hh >= Hn) continue;
#pragma unroll
            for (int j = 0; j < 3; j++) {
                int ww = w + j - 1;
                if (ww < 0 || ww >= Wn) continue;
                a += xrow[hh * Wn + ww] * swc[i * 3 + j];
            }
        }
        sXs[c][w] = a;
        sDyn[c][w] = Y2[base + (size_t)c * HWn + w];
    }
    for (int idx = threadIdx.x; idx < Cn * KK; idx += 256)
        sCf[idx] = cf[b * Cn * KK + idx];
    __syncthreads();

    // Phase A: spatial filter (9 x 64 outputs, 256-wide dot each)
    for (int idx = threadIdx.x; idx < KK * Wn; idx += 256) {
        int t = idx >> 6, w = idx & 63;
        const float* wrow = wsp + t * 256;
        float a = 0.f;
        for (int c = 0; c < Cn; c++) a += wrow[c] * sXs[c][w];
        for (int c = 0; c < Cn; c++) a += wrow[Cn + c] * sDyn[c][w];
        sSf[t][w] = a;
    }
    __syncthreads();

    // Phase B: dynamic output row (9-tap with dynamic filter)
    for (int idx = threadIdx.x; idx < Cn * Wn; idx += 256) {
        int c = idx >> 6, w = idx & 63;
        const float* xrow = X2 + (size_t)(b * Cn + c) * HWn;
        const float* cfr = sCf + c * KK;
        float a = 0.f;
#pragma unroll
        for (int i = 0; i < 3; i++) {
            int hh = h + i - 1;
            if (hh < 0 || hh >= Hn) continue;
#pragma unroll
            for (int j = 0; j < 3; j++) {
                int ww = w + j - 1;
                if (ww < 0 || ww >= Wn) continue;
                int tt = i * 3 + j;
                a += xrow[hh * Wn + ww] * (cfr[tt] + sSf[tt][w]);
            }
        }
        sDyn[c][w] = a;   // safe: Y2 copy no longer read after barrier
    }
    __syncthreads();

    // Phase C: fusion 1x1 conv, 256->128, over 64 pixels
    int w = threadIdx.x & 63;
    int og = __builtin_amdgcn_readfirstlane(threadIdx.x >> 6);  // 0..3, wave-uniform
    float acc[32];
#pragma unroll
    for (int i = 0; i < 32; i++) acc[i] = 0.f;
    for (int c = 0; c < Cn; c++) {
        float xs = sXs[c][w];
        float dn = sDyn[c][w];
#pragma unroll
        for (int i = 0; i < 32; i++) {
            int o = og * 32 + i;
            acc[i] += wf[o * 256 + c] * xs + wf[o * 256 + Cn + c] * dn;
        }
    }
#pragma unroll
    for (int i = 0; i < 32; i++) {
        int o = og * 32 + i;
        out[base + (size_t)o * HWn + w] = acc[i];
    }
}

// ---------------------------------------------------------------------------
extern "C" void kernel_launch(void* const* d_in, const int* in_sizes, int n_in,
                              void* d_out, int out_size, void* d_ws, size_t ws_size,
                              hipStream_t stream) {
    (void)in_sizes; (void)n_in; (void)out_size; (void)ws_size;
    const float* X2  = (const float*)d_in[0];
    const float* Y2  = (const float*)d_in[1];
    const float* sw  = (const float*)d_in[2];
    const float* w1  = (const float*)d_in[3];
    const float* w2  = (const float*)d_in[4];
    const float* w3  = (const float*)d_in[5];
    const float* wsp = (const float*)d_in[6];
    const float* wf  = (const float*)d_in[7];
    float* out = (float*)d_out;

    float* wsf = (float*)d_ws;          // only 45 KB of workspace used
    float* mXs = wsf;                   // 1024
    float* mY2 = wsf + 1024;            // 1024
    float* cf  = wsf + 2048;            // 8*1152

    hipLaunchKernelGGL(k_pool, dim3(Bn * Cn), dim3(256), 0, stream,
                       X2, Y2, sw, mXs, mY2);
    hipLaunchKernelGGL(k_ctx, dim3(Bn), dim3(256), 0, stream,
                       mXs, mY2, w1, w2, w3, cf);
    hipLaunchKernelGGL(k_main, dim3(Bn * Hn), dim3(256), 0, stream,
                       X2, Y2, sw, wsp, wf, cf, out);
}

// Round 2
// 202.049 us; speedup vs baseline: 1.5073x; 1.5073x over previous
//
#include <hip/hip_runtime.h>
#include <hip/hip_bf16.h>

#define Bn 8
#define Cn 128
#define Hn 64
#define Wn 64
#define HWn 4096
#define KK 9

typedef short short8 __attribute__((ext_vector_type(8)));
typedef float f32x4 __attribute__((ext_vector_type(4)));

__device__ inline short bf16r(float v) {
    __hip_bfloat16 h = __float2bfloat16(v);
    return *reinterpret_cast<short*>(&h);
}

// ---------------------------------------------------------------------------
// Kernel 0: convert wf (128 x 256 fp32, row-major) to bf16 row-major.
// ---------------------------------------------------------------------------
__global__ __launch_bounds__(256) void k_cvtwf(
    const float* __restrict__ wf, unsigned short* __restrict__ wfb)
{
    int i = blockIdx.x * 256 + threadIdx.x;
    if (i < Cn * 2 * Cn) {
        __hip_bfloat16 h = __float2bfloat16(wf[i]);
        wfb[i] = *reinterpret_cast<unsigned short*>(&h);
    }
}

// ---------------------------------------------------------------------------
// Kernel 1: per-(b,c) plane: depthwise 3x3 (recomputed, not stored) + sums of
// Xs and Y2 for the global-average-pool of the context branch.
// ---------------------------------------------------------------------------
__global__ __launch_bounds__(256) void k_pool(
    const float* __restrict__ X2, const float* __restrict__ Y2,
    const float* __restrict__ sw, float* __restrict__ mXs,
    float* __restrict__ mY2)
{
    int bc = blockIdx.x;              // b*128 + c
    int c = bc & (Cn - 1);
    const float* xp = X2 + (size_t)bc * HWn;
    const float* yp = Y2 + (size_t)bc * HWn;
    float wk[9];
#pragma unroll
    for (int i = 0; i < 9; i++) wk[i] = sw[c * 9 + i];

    float sx = 0.f, sy = 0.f;
    for (int idx = threadIdx.x; idx < HWn; idx += 256) {
        int h = idx >> 6, w = idx & 63;
        float acc = 0.f;
#pragma unroll
        for (int i = 0; i < 3; i++) {
            int hh = h + i - 1;
            if (hh < 0 || hh >= Hn) continue;
#pragma unroll
            for (int j = 0; j < 3; j++) {
                int ww = w + j - 1;
                if (ww < 0 || ww >= Wn) continue;
                acc += xp[hh * Wn + ww] * wk[i * 3 + j];
            }
        }
        sx += acc;
        sy += yp[idx];
    }
    __shared__ float r0[256], r1[256];
    int t = threadIdx.x;
    r0[t] = sx; r1[t] = sy;
    __syncthreads();
    for (int s = 128; s > 0; s >>= 1) {
        if (t < s) { r0[t] += r0[t + s]; r1[t] += r1[t + s]; }
        __syncthreads();
    }
    if (t == 0) {
        mXs[bc] = r0[0] * (1.f / HWn);
        mY2[bc] = r1[0] * (1.f / HWn);
    }
}

// ---------------------------------------------------------------------------
// Kernel 2: tiny context MLP per batch.
// ---------------------------------------------------------------------------
__global__ __launch_bounds__(256) void k_ctx(
    const float* __restrict__ mXs, const float* __restrict__ mY2,
    const float* __restrict__ w1, const float* __restrict__ w2,
    const float* __restrict__ w3, float* __restrict__ cf)
{
    int b = blockIdx.x;
    __shared__ float mfc[256], c1[64], c2[64];
    int t = threadIdx.x;
    mfc[t] = (t < Cn) ? mXs[b * Cn + t] : mY2[b * Cn + t - Cn];
    __syncthreads();
    if (t < 64) {
        float a = 0.f;
        for (int c = 0; c < 256; c++) a += w1[t * 256 + c] * mfc[c];
        c1[t] = a;
    }
    __syncthreads();
    if (t < 64) {
        float a = 0.f;
        for (int c = 0; c < 64; c++) a += w2[t * 64 + c] * c1[c];
        c2[t] = fmaxf(a, 0.f);
    }
    __syncthreads();
    for (int j = t; j < Cn * KK; j += 256) {
        float a = 0.f;
        for (int c = 0; c < 64; c++) a += w3[j * 64 + c] * c2[c];
        cf[b * Cn * KK + j] = a;
    }
}

// ---------------------------------------------------------------------------
// Kernel 3: one block per (b, h) row of 64 pixels.
//  Phase 0: recompute Xs row into LDS, load Y2 row into LDS (in sDyn).
//  Phase A: spatial filter sf[9][64] = ws @ Fc.
//  Phase B: dynamic_out row -> sDyn (overwrites Y2 copy).
//  Phase C: fusion conv via bf16 MFMA: out[128][64] = wf[128][256] @ F[256][64]
// ---------------------------------------------------------------------------
__global__ __launch_bounds__(256, 2) void k_main(
    const float* __restrict__ X2, const float* __restrict__ Y2,
    const float* __restrict__ sw, const float* __restrict__ wsp,
    const unsigned short* __restrict__ wfb, const float* __restrict__ cf,
    float* __restrict__ out)
{
    __shared__ float sXs[Cn][Wn];    // 32 KB
    __shared__ float sDyn[Cn][Wn];   // 32 KB (Y2 row, then dynamic_out row)
    __shared__ float sSf[KK][Wn];    // 2.3 KB
    __shared__ float sCf[Cn * KK];   // 4.6 KB

    int bh = blockIdx.x;
    int b = bh >> 6, h = bh & 63;
    size_t base = (size_t)b * Cn * HWn + (size_t)h * Wn;

    // Phase 0: depthwise row + Y2 row into LDS
    for (int idx = threadIdx.x; idx < Cn * Wn; idx += 256) {
        int c = idx >> 6, w = idx & 63;
        const float* xrow = X2 + (size_t)(b * Cn + c) * HWn;
        const float* swc = sw + c * 9;
        float a = 0.f;
#pragma unroll
        for (int i = 0; i < 3; i++) {
            int hh = h + i - 1;
            if (hh < 0 || hh >= Hn) continue;
#pragma unroll
            for (int j = 0; j < 3; j++) {
                int ww = w + j - 1;
                if (ww < 0 || ww >= Wn) continue;
                a += xrow[hh * Wn + ww] * swc[i * 3 + j];
            }
        }
        sXs[c][w] = a;
        sDyn[c][w] = Y2[base + (size_t)c * HWn + w];
    }
    for (int idx = threadIdx.x; idx < Cn * KK; idx += 256)
        sCf[idx] = cf[b * Cn * KK + idx];
    __syncthreads();

    // Phase A: spatial filter (9 x 64 outputs, 256-wide dot each)
    for (int idx = threadIdx.x; idx < KK * Wn; idx += 256) {
        int t = idx >> 6, w = idx & 63;
        const float* wrow = wsp + t * 256;
        float a = 0.f;
        for (int c = 0; c < Cn; c++) a += wrow[c] * sXs[c][w];
        for (int c = 0; c < Cn; c++) a += wrow[Cn + c] * sDyn[c][w];
        sSf[t][w] = a;
    }
    __syncthreads();

    // Phase B: dynamic output row (9-tap with dynamic filter)
    for (int idx = threadIdx.x; idx < Cn * Wn; idx += 256) {
        int c = idx >> 6, w = idx & 63;
        const float* xrow = X2 + (size_t)(b * Cn + c) * HWn;
        const float* cfr = sCf + c * KK;
        float a = 0.f;
#pragma unroll
        for (int i = 0; i < 3; i++) {
            int hh = h + i - 1;
            if (hh < 0 || hh >= Hn) continue;
#pragma unroll
            for (int j = 0; j < 3; j++) {
                int ww = w + j - 1;
                if (ww < 0 || ww >= Wn) continue;
                int tt = i * 3 + j;
                a += xrow[hh * Wn + ww] * (cfr[tt] + sSf[tt][w]);
            }
        }
        sDyn[c][w] = a;   // safe: Y2 copy no longer read after barrier
    }
    __syncthreads();

    // Phase C: fusion conv via MFMA (bf16 inputs, fp32 accumulate).
    // out[o][w] = sum_c wf[o][c] * F[c][w]; F = [sXs ; sDyn].
    // Wave wid owns o in [wid*32, wid*32+32): 2 m-frags x 4 n-frags, 8 k-steps.
    {
        int lane = threadIdx.x & 63;
        int wid  = threadIdx.x >> 6;
        int l16  = lane & 15;
        int half = lane >> 4;         // 0..3
        int kk   = half * 8;          // per-lane k offset within a 32-wide k-step

        f32x4 acc[2][4];
#pragma unroll
        for (int m = 0; m < 2; m++)
#pragma unroll
            for (int n = 0; n < 4; n++)
                acc[m][n] = (f32x4){0.f, 0.f, 0.f, 0.f};

#pragma unroll
        for (int ks = 0; ks < 8; ks++) {
            int k0 = ks * 32;
            const float* Fsrc = (ks < 4) ? &sXs[0][0] : &sDyn[0][0];
            int cbase = (k0 & 127) + kk;

            short8 bfrag[4];
#pragma unroll
            for (int n = 0; n < 4; n++) {
                int w = n * 16 + l16;
                short8 bv;
#pragma unroll
                for (int j = 0; j < 8; j++)
                    bv[j] = bf16r(Fsrc[(cbase + j) * Wn + w]);
                bfrag[n] = bv;
            }
#pragma unroll
            for (int m = 0; m < 2; m++) {
                const short8 av = *reinterpret_cast<const short8*>(
                    wfb + ((wid * 32 + m * 16 + l16) * 256 + k0 + kk));
#pragma unroll
                for (int n = 0; n < 4; n++)
                    acc[m][n] = __builtin_amdgcn_mfma_f32_16x16x32_bf16(
                        av, bfrag[n], acc[m][n], 0, 0, 0);
            }
        }

        // C/D layout: col = lane&15 (w), row = (lane>>4)*4 + reg (o)
#pragma unroll
        for (int m = 0; m < 2; m++)
#pragma unroll
            for (int n = 0; n < 4; n++)
#pragma unroll
                for (int r = 0; r < 4; r++) {
                    int o = wid * 32 + m * 16 + half * 4 + r;
                    int w = n * 16 + l16;
                    out[base + (size_t)o * HWn + w] = acc[m][n][r];
                }
    }
}

// ---------------------------------------------------------------------------
extern "C" void kernel_launch(void* const* d_in, const int* in_sizes, int n_in,
                              void* d_out, int out_size, void* d_ws, size_t ws_size,
                              hipStream_t stream) {
    (void)in_sizes; (void)n_in; (void)out_size; (void)ws_size;
    const float* X2  = (const float*)d_in[0];
    const float* Y2  = (const float*)d_in[1];
    const float* sw  = (const float*)d_in[2];
    const float* w1  = (const float*)d_in[3];
    const float* w2  = (const float*)d_in[4];
    const float* w3  = (const float*)d_in[5];
    const float* wsp = (const float*)d_in[6];
    const float* wf  = (const float*)d_in[7];
    float* out = (float*)d_out;

    float* wsf = (float*)d_ws;
    float* mXs = wsf;                                   // 1024 floats
    float* mY2 = wsf + 1024;                            // 1024 floats
    float* cf  = wsf + 2048;                            // 8*1152 floats
    unsigned short* wfb = (unsigned short*)(wsf + 11264); // 32768 bf16 (64 KB)

    hipLaunchKernelGGL(k_cvtwf, dim3((Cn * 2 * Cn + 255) / 256), dim3(256), 0, stream,
                       wf, wfb);
    hipLaunchKernelGGL(k_pool, dim3(Bn * Cn), dim3(256), 0, stream,
                       X2, Y2, sw, mXs, mY2);
    hipLaunchKernelGGL(k_ctx, dim3(Bn), dim3(256), 0, stream,
                       mXs, mY2, w1, w2, w3, cf);
    hipLaunchKernelGGL(k_main, dim3(Bn * Hn), dim3(256), 0, stream,
                       X2, Y2, sw, wsp, wfb, cf, out);
}

// Round 3
// 83.543 us; speedup vs baseline: 3.6453x; 2.4185x over previous
//
#include <hip/hip_runtime.h>
#include <hip/hip_bf16.h>

#define Bn 8
#define Cn 128
#define Hn 64
#define Wn 64
#define HWn 4096
#define KK 9
#define ROWP 66   // padded LDS row (u16): 132B -> 33 dwords -> bank-shift 1/row

typedef short short8 __attribute__((ext_vector_type(8)));
typedef float f32x4 __attribute__((ext_vector_type(4)));

__device__ inline unsigned short f2b(float v) {
    __hip_bfloat16 h = __float2bfloat16(v);
    return *reinterpret_cast<unsigned short*>(&h);
}
__device__ inline float b2f(unsigned short u) {
    return __uint_as_float(((unsigned int)u) << 16);
}

// ---------------------------------------------------------------------------
// K0: wf (128x256 fp32) -> bf16
// ---------------------------------------------------------------------------
__global__ __launch_bounds__(256) void k_cvtwf(
    const float* __restrict__ wf, unsigned short* __restrict__ wfb)
{
    int i = blockIdx.x * 256 + threadIdx.x;
    if (i < Cn * 2 * Cn) wfb[i] = f2b(wf[i]);
}

// ---------------------------------------------------------------------------
// K1: per (b,c) plane. Stage X2 plane in LDS, depthwise 3x3 from LDS,
// write Xs as bf16, write Y2 as bf16, block-reduce means of Xs and Y2.
// ---------------------------------------------------------------------------
__global__ __launch_bounds__(256) void k_pre(
    const float* __restrict__ X2, const float* __restrict__ Y2,
    const float* __restrict__ sw, float* __restrict__ mXs,
    float* __restrict__ mY2, unsigned short* __restrict__ XsB,
    unsigned short* __restrict__ Y2b)
{
    __shared__ float sP[HWn];
    __shared__ float r0[256], r1[256];
    int bc = blockIdx.x, c = bc & (Cn - 1), t = threadIdx.x;
    const float4* xp = (const float4*)(X2 + (size_t)bc * HWn);
    const float4* yp = (const float4*)(Y2 + (size_t)bc * HWn);

    float sy = 0.f;
#pragma unroll
    for (int i = 0; i < 4; i++) {
        int q = t + i * 256;
        float4 x = xp[q];
        ((float4*)sP)[q] = x;
        float4 y = yp[q];
        sy += y.x + y.y + y.z + y.w;
        if (Y2b) {
            ushort4 pk = { f2b(y.x), f2b(y.y), f2b(y.z), f2b(y.w) };
            ((ushort4*)(Y2b + (size_t)bc * HWn))[q] = pk;
        }
    }
    __syncthreads();

    float wk[9];
#pragma unroll
    for (int i = 0; i < 9; i++) wk[i] = sw[c * 9 + i];

    float sx = 0.f;
#pragma unroll
    for (int i = 0; i < 16; i++) {
        int px = t + i * 256;
        int h = px >> 6, w = px & 63;
        float a = 0.f;
#pragma unroll
        for (int dh = -1; dh <= 1; dh++) {
            int hh = h + dh;
            if (hh < 0 || hh >= Hn) continue;
#pragma unroll
            for (int dw = -1; dw <= 1; dw++) {
                int ww = w + dw;
                if (ww < 0 || ww >= Wn) continue;
                a += sP[hh * Wn + ww] * wk[(dh + 1) * 3 + dw + 1];
            }
        }
        sx += a;
        if (XsB) XsB[(size_t)bc * HWn + px] = f2b(a);
    }
    r0[t] = sx; r1[t] = sy;
    __syncthreads();
    for (int s = 128; s > 0; s >>= 1) {
        if (t < s) { r0[t] += r0[t + s]; r1[t] += r1[t + s]; }
        __syncthreads();
    }
    if (t == 0) {
        mXs[bc] = r0[0] * (1.f / HWn);
        mY2[bc] = r1[0] * (1.f / HWn);
    }
}

// ---------------------------------------------------------------------------
// K2: tiny context MLP per batch.
// ---------------------------------------------------------------------------
__global__ __launch_bounds__(256) void k_ctx(
    const float* __restrict__ mXs, const float* __restrict__ mY2,
    const float* __restrict__ w1, const float* __restrict__ w2,
    const float* __restrict__ w3, float* __restrict__ cf)
{
    int b = blockIdx.x;
    __shared__ float mfc[256], c1[64], c2[64];
    int t = threadIdx.x;
    mfc[t] = (t < Cn) ? mXs[b * Cn + t] : mY2[b * Cn + t - Cn];
    __syncthreads();
    if (t < 64) {
        const float4* wr = (const float4*)(w1 + t * 256);
        float a = 0.f;
        for (int c = 0; c < 64; c++) {
            float4 v = wr[c];
            a += v.x * mfc[c*4] + v.y * mfc[c*4+1] + v.z * mfc[c*4+2] + v.w * mfc[c*4+3];
        }
        c1[t] = a;
    }
    __syncthreads();
    if (t < 64) {
        const float4* wr = (const float4*)(w2 + t * 64);
        float a = 0.f;
        for (int c = 0; c < 16; c++) {
            float4 v = wr[c];
            a += v.x * c1[c*4] + v.y * c1[c*4+1] + v.z * c1[c*4+2] + v.w * c1[c*4+3];
        }
        c2[t] = fmaxf(a, 0.f);
    }
    __syncthreads();
    for (int j = t; j < Cn * KK; j += 256) {
        const float4* wr = (const float4*)(w3 + j * 64);
        float a = 0.f;
        for (int c = 0; c < 16; c++) {
            float4 v = wr[c];
            a += v.x * c2[c*4] + v.y * c2[c*4+1] + v.z * c2[c*4+2] + v.w * c2[c*4+3];
        }
        cf[b * Cn * KK + j] = a;
    }
}

// ---------------------------------------------------------------------------
// K3: one block per (b,h) row. bf16 LDS tiles (padded rows).
//  Phase 0: load XsB/Y2b rows (or recompute if no workspace).
//  Phase A: spatial filter sf[9][64].
//  Phase B: dynamic out row (3 loads + shfl neighbors per tap-row).
//  Phase C: fusion GEMM via bf16 MFMA.
// ---------------------------------------------------------------------------
__global__ __launch_bounds__(256, 4) void k_main(
    const float* __restrict__ X2, const float* __restrict__ Y2,
    const float* __restrict__ sw, const float* __restrict__ wsp,
    const unsigned short* __restrict__ wfb, const float* __restrict__ cf,
    const unsigned short* __restrict__ XsB, const unsigned short* __restrict__ Y2b,
    float* __restrict__ out)
{
    __shared__ unsigned short sF[2][Cn][ROWP];   // [0]=Xs, [1]=Y2 then dyn
    __shared__ float sSf[KK][Wn];
    __shared__ float sCf[Cn * KK];

    int bid = blockIdx.x;
    int b = bid & 7, h = bid >> 3;       // XCD-chunked: each XCD owns one batch
    int t = threadIdx.x;
    size_t base = (size_t)b * Cn * HWn + (size_t)h * Wn;

    // ---- Phase 0
    if (XsB) {
        int c0 = t >> 4, wq = t & 15;
#pragma unroll
        for (int i = 0; i < 8; i++) {
            int c = c0 + 16 * i;
            size_t goff = (size_t)(b * Cn + c) * HWn + h * Wn + wq * 4;
            ushort4 xv = *(const ushort4*)(XsB + goff);
            ushort4 yv = *(const ushort4*)(Y2b + goff);
            unsigned int* dx = (unsigned int*)&sF[0][c][wq * 4];
            dx[0] = ((unsigned int)xv.y << 16) | xv.x;
            dx[1] = ((unsigned int)xv.w << 16) | xv.z;
            unsigned int* dy = (unsigned int*)&sF[1][c][wq * 4];
            dy[0] = ((unsigned int)yv.y << 16) | yv.x;
            dy[1] = ((unsigned int)yv.w << 16) | yv.z;
        }
    } else {
        for (int idx = t; idx < Cn * Wn; idx += 256) {
            int c = idx >> 6, w = idx & 63;
            const float* xrow = X2 + (size_t)(b * Cn + c) * HWn;
            const float* swc = sw + c * 9;
            float a = 0.f;
#pragma unroll
            for (int i = 0; i < 3; i++) {
                int hh = h + i - 1;
                if (hh < 0 || hh >= Hn) continue;
#pragma unroll
                for (int j = 0; j < 3; j++) {
                    int ww = w + j - 1;
                    if (ww < 0 || ww >= Wn) continue;
                    a += xrow[hh * Wn + ww] * swc[i * 3 + j];
                }
            }
            sF[0][c][w] = f2b(a);
            sF[1][c][w] = f2b(Y2[base + (size_t)c * HWn + w]);
        }
    }
    for (int idx = t; idx < Cn * KK; idx += 256) sCf[idx] = cf[b * Cn * KK + idx];
    __syncthreads();

    // ---- Phase A: sf[t][w] = sum_c ws[t][c]*Xs[c][w] + ws[t][128+c]*Y2[c][w]
    for (int idx = t; idx < KK * Wn; idx += 256) {
        int tt = idx >> 6, w = idx & 63;
        const float* wr = wsp + tt * 256;
        float a = 0.f;
        for (int c = 0; c < Cn; c++) a += wr[c] * b2f(sF[0][c][w]);
        for (int c = 0; c < Cn; c++) a += wr[Cn + c] * b2f(sF[1][c][w]);
        sSf[tt][w] = a;
    }
    __syncthreads();

    // ---- Phase B: dyn[c][w] = sum_{taps} X2patch * (cf[c][t] + sf[t][w])
    {
        int w = t & 63, cg = t >> 6;
        float sfw[9];
#pragma unroll
        for (int q = 0; q < 9; q++) sfw[q] = sSf[q][w];
        for (int i = 0; i < 32; i++) {
            int c = cg * 32 + i;
            const float* cfr = sCf + c * 9;
            const float* xr = X2 + (size_t)(b * Cn + c) * HWn + h * Wn;
            float a = 0.f;
#pragma unroll
            for (int dh = -1; dh <= 1; dh++) {
                int hh = h + dh;
                float xc = (hh >= 0 && hh < Hn) ? xr[dh * Wn + w] : 0.f;
                float xl = __shfl_up(xc, 1);
                float xrr = __shfl_down(xc, 1);
                if (w == 0)  xl = 0.f;
                if (w == 63) xrr = 0.f;
                int tb = (dh + 1) * 3;
                a += xl  * (cfr[tb]     + sfw[tb]);
                a += xc  * (cfr[tb + 1] + sfw[tb + 1]);
                a += xrr * (cfr[tb + 2] + sfw[tb + 2]);
            }
            sF[1][c][w] = f2b(a);
        }
    }
    __syncthreads();

    // ---- Phase C: out[o][w] = sum_k wf[o][k] * F[k][w], K=256 (Xs;dyn)
    {
        int lane = t & 63, wid = t >> 6;
        int l16 = lane & 15, half = lane >> 4, kk = half * 8;

        f32x4 acc[2][4];
#pragma unroll
        for (int m = 0; m < 2; m++)
#pragma unroll
            for (int n = 0; n < 4; n++)
                acc[m][n] = (f32x4){0.f, 0.f, 0.f, 0.f};

#pragma unroll
        for (int ks = 0; ks < 8; ks++) {
            int k0 = ks * 32;
            int bufi = ks >> 2;
            int cbase = (k0 & 127) + kk;

            short8 bfrag[4];
#pragma unroll
            for (int n = 0; n < 4; n++) {
                int w = n * 16 + l16;
                short8 bv;
#pragma unroll
                for (int j = 0; j < 8; j++)
                    bv[j] = (short)sF[bufi][cbase + j][w];
                bfrag[n] = bv;
            }
#pragma unroll
            for (int m = 0; m < 2; m++) {
                const short8 av = *reinterpret_cast<const short8*>(
                    wfb + ((wid * 32 + m * 16 + l16) * 256 + k0 + kk));
#pragma unroll
                for (int n = 0; n < 4; n++)
                    acc[m][n] = __builtin_amdgcn_mfma_f32_16x16x32_bf16(
                        av, bfrag[n], acc[m][n], 0, 0, 0);
            }
        }
#pragma unroll
        for (int m = 0; m < 2; m++)
#pragma unroll
            for (int n = 0; n < 4; n++)
#pragma unroll
                for (int r = 0; r < 4; r++) {
                    int o = wid * 32 + m * 16 + half * 4 + r;
                    int w = n * 16 + l16;
                    out[base + (size_t)o * HWn + w] = acc[m][n][r];
                }
    }
}

// ---------------------------------------------------------------------------
extern "C" void kernel_launch(void* const* d_in, const int* in_sizes, int n_in,
                              void* d_out, int out_size, void* d_ws, size_t ws_size,
                              hipStream_t stream) {
    (void)in_sizes; (void)n_in; (void)out_size;
    const float* X2  = (const float*)d_in[0];
    const float* Y2  = (const float*)d_in[1];
    const float* sw  = (const float*)d_in[2];
    const float* w1  = (const float*)d_in[3];
    const float* w2  = (const float*)d_in[4];
    const float* w3  = (const float*)d_in[5];
    const float* wsp = (const float*)d_in[6];
    const float* wf  = (const float*)d_in[7];
    float* out = (float*)d_out;

    float* wsf = (float*)d_ws;
    float* mXs = wsf;                                     // 1024 f
    float* mY2 = wsf + 1024;                              // 1024 f
    float* cf  = wsf + 2048;                              // 9216 f
    unsigned short* wfb = (unsigned short*)(wsf + 11264); // 32768 u16

    // Optional big scratch: Xs and Y2 as bf16 planes (8 MB each).
    const size_t need = (size_t)(27648 + 2 * 2097152) * 4;  // 16.9 MB
    bool pre = ws_size >= need;
    unsigned short* XsB = pre ? (unsigned short*)(wsf + 27648) : nullptr;
    unsigned short* Y2b = pre ? (unsigned short*)(wsf + 27648 + 2097152) : nullptr;

    hipLaunchKernelGGL(k_cvtwf, dim3(128), dim3(256), 0, stream, wf, wfb);
    hipLaunchKernelGGL(k_pre, dim3(Bn * Cn), dim3(256), 0, stream,
                       X2, Y2, sw, mXs, mY2, XsB, Y2b);
    hipLaunchKernelGGL(k_ctx, dim3(Bn), dim3(256), 0, stream,
                       mXs, mY2, w1, w2, w3, cf);
    hipLaunchKernelGGL(k_main, dim3(Bn * Hn), dim3(256), 0, stream,
                       X2, Y2, sw, wsp, wfb, cf, XsB, Y2b, out);
}

// Round 4
// 70.281 us; speedup vs baseline: 4.3332x; 1.1887x over previous
//
#include <hip/hip_runtime.h>
#include <hip/hip_bf16.h>

#define Bn 8
#define Cn 128
#define Hn 64
#define Wn 64
#define HWn 4096
#define KK 9

typedef short short8 __attribute__((ext_vector_type(8)));
typedef float f32x4 __attribute__((ext_vector_type(4)));

__device__ inline unsigned short f2b(float v) {
    __hip_bfloat16 h = __float2bfloat16(v);
    return *reinterpret_cast<unsigned short*>(&h);
}
__device__ inline float b2f(unsigned short u) {
    return __uint_as_float(((unsigned int)u) << 16);
}

// ---------------------------------------------------------------------------
// K1: per (b,c) plane. Stage X2 plane in LDS, vectorized depthwise 3x3,
// write Xs bf16 + Y2 bf16 planes, block-reduce means.
// ---------------------------------------------------------------------------
__global__ __launch_bounds__(256) void k_pre(
    const float* __restrict__ X2, const float* __restrict__ Y2,
    const float* __restrict__ sw, float* __restrict__ mXs,
    float* __restrict__ mY2, unsigned short* __restrict__ XsB,
    unsigned short* __restrict__ Y2b)
{
    __shared__ float sP[HWn];
    __shared__ float r0[256], r1[256];
    int bc = blockIdx.x, c = bc & (Cn - 1), t = threadIdx.x;
    const float4* xp = (const float4*)(X2 + (size_t)bc * HWn);
    const float4* yp = (const float4*)(Y2 + (size_t)bc * HWn);

    float sy = 0.f;
#pragma unroll
    for (int i = 0; i < 4; i++) {
        int q = t + i * 256;
        float4 x = xp[q];
        ((float4*)sP)[q] = x;
        float4 y = yp[q];
        sy += y.x + y.y + y.z + y.w;
        if (Y2b) {
            ushort4 pk = { f2b(y.x), f2b(y.y), f2b(y.z), f2b(y.w) };
            ((ushort4*)(Y2b + (size_t)bc * HWn))[q] = pk;
        }
    }
    __syncthreads();

    float wk[9];
#pragma unroll
    for (int i = 0; i < 9; i++) wk[i] = sw[c * 9 + i];

    float sx = 0.f;
#pragma unroll
    for (int g = 0; g < 4; g++) {
        int grp = t + g * 256;           // 1024 groups of 4 px
        int h = grp >> 4, w4 = (grp & 15) * 4;
        float o0 = 0.f, o1 = 0.f, o2 = 0.f, o3 = 0.f;
#pragma unroll
        for (int dh = -1; dh <= 1; dh++) {
            int hh = h + dh;
            if (hh < 0 || hh >= Hn) continue;
            const float* row = sP + hh * Wn;
            float4 a = *(const float4*)(row + w4);
            float xm = (w4 > 0)  ? row[w4 - 1] : 0.f;
            float xq = (w4 < 60) ? row[w4 + 4] : 0.f;
            float k0 = wk[(dh + 1) * 3], k1 = wk[(dh + 1) * 3 + 1], k2 = wk[(dh + 1) * 3 + 2];
            o0 += k0 * xm  + k1 * a.x + k2 * a.y;
            o1 += k0 * a.x + k1 * a.y + k2 * a.z;
            o2 += k0 * a.y + k1 * a.z + k2 * a.w;
            o3 += k0 * a.z + k1 * a.w + k2 * xq;
        }
        sx += o0 + o1 + o2 + o3;
        if (XsB) {
            ushort4 pk = { f2b(o0), f2b(o1), f2b(o2), f2b(o3) };
            *(ushort4*)(XsB + (size_t)bc * HWn + grp * 4) = pk;
        }
    }
    r0[t] = sx; r1[t] = sy;
    __syncthreads();
    for (int s = 128; s > 0; s >>= 1) {
        if (t < s) { r0[t] += r0[t + s]; r1[t] += r1[t + s]; }
        __syncthreads();
    }
    if (t == 0) {
        mXs[bc] = r0[0] * (1.f / HWn);
        mY2[bc] = r1[0] * (1.f / HWn);
    }
}

// ---------------------------------------------------------------------------
// K2: tiny context MLP per batch + wf/ws bf16 conversion slices.
// ---------------------------------------------------------------------------
__global__ __launch_bounds__(256) void k_ctx(
    const float* __restrict__ mXs, const float* __restrict__ mY2,
    const float* __restrict__ w1, const float* __restrict__ w2,
    const float* __restrict__ w3, const float* __restrict__ wf,
    const float* __restrict__ wsp, float* __restrict__ cf,
    unsigned short* __restrict__ wfb, unsigned short* __restrict__ wsb)
{
    int b = blockIdx.x;
    int t = threadIdx.x;

    // weight conversion slices (independent of MLP)
    {
        int boff = b * 4096;
        for (int i = t; i < 4096; i += 256) wfb[boff + i] = f2b(wf[boff + i]);
        for (int i = t; i < 512; i += 256) {
            int j = b * 512 + i;           // covers 16*256
            int tt = j >> 8, c = j & 255;
            wsb[j] = (tt < KK) ? f2b(wsp[tt * 256 + c]) : (unsigned short)0;
        }
    }

    __shared__ float mfc[256], c1[64], c2[64];
    mfc[t] = (t < Cn) ? mXs[b * Cn + t] : mY2[b * Cn + t - Cn];
    __syncthreads();
    if (t < 64) {
        const float4* wr = (const float4*)(w1 + t * 256);
        float a = 0.f;
        for (int c = 0; c < 64; c++) {
            float4 v = wr[c];
            a += v.x * mfc[c*4] + v.y * mfc[c*4+1] + v.z * mfc[c*4+2] + v.w * mfc[c*4+3];
        }
        c1[t] = a;
    }
    __syncthreads();
    if (t < 64) {
        const float4* wr = (const float4*)(w2 + t * 64);
        float a = 0.f;
        for (int c = 0; c < 16; c++) {
            float4 v = wr[c];
            a += v.x * c1[c*4] + v.y * c1[c*4+1] + v.z * c1[c*4+2] + v.w * c1[c*4+3];
        }
        c2[t] = fmaxf(a, 0.f);
    }
    __syncthreads();
    for (int j = t; j < Cn * KK; j += 256) {
        const float4* wr = (const float4*)(w3 + j * 64);
        float a = 0.f;
        for (int c = 0; c < 16; c++) {
            float4 v = wr[c];
            a += v.x * c2[c*4] + v.y * c2[c*4+1] + v.z * c2[c*4+2] + v.w * c2[c*4+3];
        }
        cf[b * Cn * KK + j] = a;
    }
}

// ---------------------------------------------------------------------------
// K3: one block per (b,h) row. Transposed swizzled bf16 LDS:
//   sFt[buf][w][c ^ ((w&7)<<3)]  (rows 256B, b128-friendly, conflict-light)
//  Phase 0: coalesced loads of XsB/Y2b rows -> swizzled LDS transpose.
//  Phase A: spatial filter via one MFMA chain (wsb 16x256 zero-padded).
//  Phase B: dynamic out (global X2 taps + shfl), b64 swizzled writes.
//  Phase C: fusion GEMM via MFMA, B-frags ds_read_b128.
// ---------------------------------------------------------------------------
__global__ __launch_bounds__(256, 4) void k_main(
    const float* __restrict__ X2, const float* __restrict__ Y2,
    const float* __restrict__ sw, const float* __restrict__ wsp,
    const unsigned short* __restrict__ wfb, const unsigned short* __restrict__ wsb,
    const float* __restrict__ cf,
    const unsigned short* __restrict__ XsB, const unsigned short* __restrict__ Y2b,
    float* __restrict__ out)
{
    __shared__ unsigned short sFt[2][Wn][Cn];   // 32 KB, swizzled columns
    __shared__ float sSf[KK][Wn];               // 2.25 KB
    __shared__ float sCf[Cn * KK];              // 4.5 KB

    int bid = blockIdx.x;
    int b = bid & 7, h = bid >> 3;       // XCD-chunked: each XCD owns one batch
    int t = threadIdx.x;
    size_t base = (size_t)b * Cn * HWn + (size_t)h * Wn;

    // ---- Phase 0: load + swizzled LDS transpose
    if (XsB) {
        int c0 = t >> 4, wq = t & 15;
#pragma unroll
        for (int i = 0; i < 8; i++) {
            int c = c0 + 16 * i;
            size_t g = (size_t)(b * Cn + c) * HWn + h * Wn + wq * 4;
            ushort4 xv = *(const ushort4*)(XsB + g);
            ushort4 yv = *(const ushort4*)(Y2b + g);
            const unsigned short* xa = (const unsigned short*)&xv;
            const unsigned short* ya = (const unsigned short*)&yv;
#pragma unroll
            for (int j = 0; j < 4; j++) {
                int w = wq * 4 + j;
                int col = c ^ ((w & 7) << 3);
                sFt[0][w][col] = xa[j];
                sFt[1][w][col] = ya[j];
            }
        }
    } else {
        for (int idx = t; idx < Cn * Wn; idx += 256) {
            int c = idx >> 6, w = idx & 63;
            const float* xrow = X2 + (size_t)(b * Cn + c) * HWn;
            const float* swc = sw + c * 9;
            float a = 0.f;
#pragma unroll
            for (int i = 0; i < 3; i++) {
                int hh = h + i - 1;
                if (hh < 0 || hh >= Hn) continue;
#pragma unroll
                for (int j = 0; j < 3; j++) {
                    int ww = w + j - 1;
                    if (ww < 0 || ww >= Wn) continue;
                    a += xrow[hh * Wn + ww] * swc[i * 3 + j];
                }
            }
            int col = c ^ ((w & 7) << 3);
            sFt[0][w][col] = f2b(a);
            sFt[1][w][col] = f2b(Y2[base + (size_t)c * HWn + w]);
        }
    }
    for (int idx = t; idx < Cn * KK; idx += 256) sCf[idx] = cf[b * Cn * KK + idx];
    __syncthreads();

    // ---- Phase A: sf[16][64] = wsb[16][256] @ F[256][64]  (rows 9..15 zero)
    {
        int lane = t & 63, wid = t >> 6;
        int l16 = lane & 15, half = lane >> 4, kk = half * 8;
        int w = wid * 16 + l16;
        int swz = (w & 7) << 3;
        f32x4 acc = (f32x4){0.f, 0.f, 0.f, 0.f};
#pragma unroll
        for (int ks = 0; ks < 8; ks++) {
            short8 av = *(const short8*)(wsb + l16 * 256 + ks * 32 + kk);
            int col = (((ks & 3) * 32 + kk)) ^ swz;
            short8 bv = *(const short8*)(&sFt[ks >> 2][w][0] + col);
            acc = __builtin_amdgcn_mfma_f32_16x16x32_bf16(av, bv, acc, 0, 0, 0);
        }
#pragma unroll
        for (int r = 0; r < 4; r++) {
            int tt = half * 4 + r;
            if (tt < KK) sSf[tt][w] = acc[r];
        }
    }
    __syncthreads();

    // ---- Phase B: dyn[c][w] = sum_taps X2patch * (cf[c][t] + sf[t][w])
    {
        int w = t & 63, cg = t >> 6;
        int swz = (w & 7) << 3;
        float sfw[9];
#pragma unroll
        for (int q = 0; q < 9; q++) sfw[q] = sSf[q][w];
        unsigned int buf0 = 0, buf1 = 0;
        for (int i = 0; i < 32; i++) {
            int c = cg * 32 + i;
            const float* cfr = sCf + c * 9;
            const float* xr = X2 + (size_t)(b * Cn + c) * HWn + h * Wn;
            float a = 0.f;
#pragma unroll
            for (int dh = -1; dh <= 1; dh++) {
                int hh = h + dh;
                float xc = (hh >= 0 && hh < Hn) ? xr[dh * Wn + w] : 0.f;
                float xl = __shfl_up(xc, 1);
                float xrr = __shfl_down(xc, 1);
                if (w == 0)  xl = 0.f;
                if (w == 63) xrr = 0.f;
                int tb = (dh + 1) * 3;
                a += xl  * (cfr[tb]     + sfw[tb]);
                a += xc  * (cfr[tb + 1] + sfw[tb + 1]);
                a += xrr * (cfr[tb + 2] + sfw[tb + 2]);
            }
            unsigned int hv = f2b(a);
            int sub = i & 3;
            if (sub == 0)      buf0 = hv;
            else if (sub == 1) buf0 |= hv << 16;
            else if (sub == 2) buf1 = hv;
            else {
                buf1 |= hv << 16;
                int col = (c - 3) ^ swz;
                uint2 pk; pk.x = buf0; pk.y = buf1;
                *(uint2*)(&sFt[1][w][col]) = pk;
            }
        }
    }
    __syncthreads();

    // ---- Phase C: out[o][w] = sum_k wf[o][k] * F[k][w], K=256
    {
        int lane = t & 63, wid = t >> 6;
        int l16 = lane & 15, half = lane >> 4, kk = half * 8;

        f32x4 acc[2][4];
#pragma unroll
        for (int m = 0; m < 2; m++)
#pragma unroll
            for (int n = 0; n < 4; n++)
                acc[m][n] = (f32x4){0.f, 0.f, 0.f, 0.f};

#pragma unroll
        for (int ks = 0; ks < 8; ks++) {
            int k0 = ks * 32, bufi = ks >> 2;
            int kc = (k0 & 127) + kk;
            short8 bfrag[4];
#pragma unroll
            for (int n = 0; n < 4; n++) {
                int w = n * 16 + l16;
                int col = kc ^ ((w & 7) << 3);
                bfrag[n] = *(const short8*)(&sFt[bufi][w][0] + col);
            }
#pragma unroll
            for (int m = 0; m < 2; m++) {
                const short8 av = *reinterpret_cast<const short8*>(
                    wfb + ((wid * 32 + m * 16 + l16) * 256 + k0 + kk));
#pragma unroll
                for (int n = 0; n < 4; n++)
                    acc[m][n] = __builtin_amdgcn_mfma_f32_16x16x32_bf16(
                        av, bfrag[n], acc[m][n], 0, 0, 0);
            }
        }
#pragma unroll
        for (int m = 0; m < 2; m++)
#pragma unroll
            for (int n = 0; n < 4; n++)
#pragma unroll
                for (int r = 0; r < 4; r++) {
                    int o = wid * 32 + m * 16 + half * 4 + r;
                    int w = n * 16 + l16;
                    out[base + (size_t)o * HWn + w] = acc[m][n][r];
                }
    }
}

// ---------------------------------------------------------------------------
extern "C" void kernel_launch(void* const* d_in, const int* in_sizes, int n_in,
                              void* d_out, int out_size, void* d_ws, size_t ws_size,
                              hipStream_t stream) {
    (void)in_sizes; (void)n_in; (void)out_size;
    const float* X2  = (const float*)d_in[0];
    const float* Y2  = (const float*)d_in[1];
    const float* sw  = (const float*)d_in[2];
    const float* w1  = (const float*)d_in[3];
    const float* w2  = (const float*)d_in[4];
    const float* w3  = (const float*)d_in[5];
    const float* wsp = (const float*)d_in[6];
    const float* wf  = (const float*)d_in[7];
    float* out = (float*)d_out;

    float* wsf = (float*)d_ws;
    float* mXs = wsf;                                     // 1024 f
    float* mY2 = wsf + 1024;                              // 1024 f
    float* cf  = wsf + 2048;                              // 9216 f
    unsigned short* wfb = (unsigned short*)(wsf + 11264); // 32768 u16
    unsigned short* wsb = (unsigned short*)(wsf + 27648); // 4096 u16
    // big scratch: Xs and Y2 bf16 planes (8 MB each)
    const size_t need = (size_t)(29696 + 2 * 2097152) * 4;
    bool pre = ws_size >= need;
    unsigned short* XsB = pre ? (unsigned short*)(wsf + 29696) : nullptr;
    unsigned short* Y2b = pre ? (unsigned short*)(wsf + 29696 + 2097152) : nullptr;

    hipLaunchKernelGGL(k_pre, dim3(Bn * Cn), dim3(256), 0, stream,
                       X2, Y2, sw, mXs, mY2, XsB, Y2b);
    hipLaunchKernelGGL(k_ctx, dim3(Bn), dim3(256), 0, stream,
                       mXs, mY2, w1, w2, w3, wf, wsp, cf, wfb, wsb);
    hipLaunchKernelGGL(k_main, dim3(Bn * Hn), dim3(256), 0, stream,
                       X2, Y2, sw, wsp, wfb, wsb, cf, XsB, Y2b, out);
}

// Round 5
// 56.532 us; speedup vs baseline: 5.3871x; 1.2432x over previous
//
#include <hip/hip_runtime.h>
#include <hip/hip_bf16.h>

#define Bn 8
#define Cn 128
#define Hn 64
#define Wn 64
#define HWn 4096
#define KK 9

typedef short short8 __attribute__((ext_vector_type(8)));
typedef float f32x4 __attribute__((ext_vector_type(4)));

__device__ inline unsigned short f2b(float v) {
    __hip_bfloat16 h = __float2bfloat16(v);
    return *reinterpret_cast<unsigned short*>(&h);
}

// ---------------------------------------------------------------------------
// K1: per-(b,c) plane streaming sums: T_x, rowsum0, rowsum63, colsum0,
// colsum63 (X2), T_y (Y2). mean(Xs) is reconstructed algebraically in k_ctx.
// ---------------------------------------------------------------------------
__global__ __launch_bounds__(256) void k_pre(
    const float* __restrict__ X2, const float* __restrict__ Y2,
    float* __restrict__ pws)
{
    int bc = blockIdx.x, t = threadIdx.x;
    const float4* xp = (const float4*)(X2 + (size_t)bc * HWn);
    const float4* yp = (const float4*)(Y2 + (size_t)bc * HWn);
    float v[6] = {0.f, 0.f, 0.f, 0.f, 0.f, 0.f};
#pragma unroll
    for (int i = 0; i < 4; i++) {
        int q = t + i * 256;
        float4 x = xp[q], y = yp[q];
        float s4 = x.x + x.y + x.z + x.w;
        v[0] += s4;
        v[5] += y.x + y.y + y.z + y.w;
        int px = q * 4, h = px >> 6, w4 = px & 63;
        if (h == 0)   v[1] += s4;
        if (h == 63)  v[2] += s4;
        if (w4 == 0)  v[3] += x.x;
        if (w4 == 60) v[4] += x.w;
    }
#pragma unroll
    for (int k = 0; k < 6; k++)
#pragma unroll
        for (int off = 32; off; off >>= 1)
            v[k] += __shfl_down(v[k], off);
    __shared__ float red[4][6];
    int lane = t & 63, wv = t >> 6;
    if (lane == 0) {
#pragma unroll
        for (int k = 0; k < 6; k++) red[wv][k] = v[k];
    }
    __syncthreads();
    if (t < 6) pws[bc * 6 + t] = red[0][t] + red[1][t] + red[2][t] + red[3][t];
}

// ---------------------------------------------------------------------------
// K2: closed-form mean(Xs) + mean(Y2) -> context MLP -> cf. Also converts
// wf and ws (zero-padded 16x256) to bf16 in slices.
// ---------------------------------------------------------------------------
__global__ __launch_bounds__(256) void k_ctx(
    const float* __restrict__ X2, const float* __restrict__ pws,
    const float* __restrict__ sw,
    const float* __restrict__ w1, const float* __restrict__ w2,
    const float* __restrict__ w3, const float* __restrict__ wf,
    const float* __restrict__ wsp, float* __restrict__ cf,
    unsigned short* __restrict__ wfb, unsigned short* __restrict__ wsb)
{
    int b = blockIdx.x, t = threadIdx.x;
    {
        int boff = b * 4096;
        for (int i = t; i < 4096; i += 256) wfb[boff + i] = f2b(wf[boff + i]);
        for (int i = t; i < 512; i += 256) {
            int j = b * 512 + i, tt = j >> 8, c = j & 255;
            wsb[j] = (tt < KK) ? f2b(wsp[tt * 256 + c]) : (unsigned short)0;
        }
    }
    __shared__ float mfc[256], c1[64], c2[64];
    if (t < 128) {
        int bc = b * Cn + t;
        const float* S = pws + bc * 6;
        const float* pl = X2 + (size_t)bc * HWn;
        float T = S[0];
        // i=0 excludes row 63; i=2 excludes row 0. j likewise for cols.
        float R[3]  = { S[2], 0.f, S[1] };
        float Cc[3] = { S[4], 0.f, S[3] };
        float x00 = pl[0], x063 = pl[63], x630 = pl[63 * 64], x6363 = pl[4095];
        float Xc[3][3] = {{x6363, 0.f, x630}, {0.f, 0.f, 0.f}, {x063, 0.f, x00}};
        float a = 0.f;
#pragma unroll
        for (int i = 0; i < 3; i++)
#pragma unroll
            for (int j = 0; j < 3; j++)
                a += sw[t * 9 + i * 3 + j] * (T - R[i] - Cc[j] + Xc[i][j]);
        mfc[t] = a * (1.f / HWn);
    } else {
        mfc[t] = pws[(b * Cn + (t - 128)) * 6 + 5] * (1.f / HWn);
    }
    __syncthreads();
    if (t < 64) {
        const float4* wr = (const float4*)(w1 + t * 256);
        float a = 0.f;
        for (int c = 0; c < 64; c++) {
            float4 v = wr[c];
            a += v.x * mfc[c*4] + v.y * mfc[c*4+1] + v.z * mfc[c*4+2] + v.w * mfc[c*4+3];
        }
        c1[t] = a;
    }
    __syncthreads();
    if (t < 64) {
        const float4* wr = (const float4*)(w2 + t * 64);
        float a = 0.f;
        for (int c = 0; c < 16; c++) {
            float4 v = wr[c];
            a += v.x * c1[c*4] + v.y * c1[c*4+1] + v.z * c1[c*4+2] + v.w * c1[c*4+3];
        }
        c2[t] = fmaxf(a, 0.f);
    }
    __syncthreads();
    for (int j = t; j < Cn * KK; j += 256) {
        const float4* wr = (const float4*)(w3 + j * 64);
        float a = 0.f;
        for (int c = 0; c < 16; c++) {
            float4 v = wr[c];
            a += v.x * c2[c*4] + v.y * c2[c*4+1] + v.z * c2[c*4+2] + v.w * c2[c*4+3];
        }
        cf[b * Cn * KK + j] = a;
    }
}

// ---------------------------------------------------------------------------
// K3: one block per (b, h, w-half). 256 threads, ~27 KB LDS -> 4 blocks/CU.
//  Phase 0: recompute Xs tile (9 predicated taps from X2, L2-hot) + Y2 tile
//           into swizzled bf16 LDS, b64-packed writes.
//  Phase A: spatial filter sf[9][32] via MFMA (waves 0-1).
//  Phase B: dynamic out (tap reload, L1/L2-hot) -> sFt[1].
//  Phase C: fusion GEMM out[128][32] = wf[128][256] @ [Xs;dyn] via MFMA.
// ---------------------------------------------------------------------------
__global__ __launch_bounds__(256, 4) void k_main(
    const float* __restrict__ X2, const float* __restrict__ Y2,
    const float* __restrict__ sw,
    const unsigned short* __restrict__ wfb, const unsigned short* __restrict__ wsb,
    const float* __restrict__ cf, float* __restrict__ out)
{
    __shared__ unsigned short sFt[2][32][Cn];  // 16 KB, col swizzled c^((w&7)<<3)
    __shared__ float sSf[KK][32];              // 1.1 KB
    __shared__ float sCf[Cn * KK];             // 4.5 KB
    __shared__ float sSw[Cn * KK];             // 4.5 KB

    int bid = blockIdx.x;
    int b = bid & 7, rest = bid >> 3;          // XCD-chunked: batch b per XCD
    int wh = rest & 1, h = rest >> 1;
    int w0 = wh * 32;
    int t = threadIdx.x;
    int w = t & 31, cg = t >> 5;
    int wg = w0 + w;
    int swz = (w & 7) << 3;

    for (int i = t; i < Cn * KK; i += 256) {
        sSw[i] = sw[i];
        sCf[i] = cf[b * Cn * KK + i];
    }
    __syncthreads();

    const float* xbase = X2 + (size_t)b * Cn * HWn + h * Wn + wg;
    const float* ybase = Y2 + (size_t)b * Cn * HWn + h * Wn + wg;
    bool hm = h > 0, hp = h < Hn - 1;
    bool wm = wg > 0, wp = wg < Wn - 1;

    // ---- Phase 0
    {
        unsigned int px0 = 0, px1 = 0, py0 = 0, py1 = 0;
#pragma unroll 4
        for (int i = 0; i < 16; i++) {
            int c = cg * 16 + i;
            const float* xp = xbase + (size_t)c * HWn;
            float tp[9];
            tp[0] = (hm && wm) ? xp[-Wn - 1] : 0.f;
            tp[1] = hm ? xp[-Wn] : 0.f;
            tp[2] = (hm && wp) ? xp[-Wn + 1] : 0.f;
            tp[3] = wm ? xp[-1] : 0.f;
            tp[4] = xp[0];
            tp[5] = wp ? xp[1] : 0.f;
            tp[6] = (hp && wm) ? xp[Wn - 1] : 0.f;
            tp[7] = hp ? xp[Wn] : 0.f;
            tp[8] = (hp && wp) ? xp[Wn + 1] : 0.f;
            const float* wkp = sSw + c * 9;
            float a = 0.f;
#pragma unroll
            for (int q = 0; q < 9; q++) a += tp[q] * wkp[q];
            float yv = ybase[(size_t)c * HWn];
            unsigned int ah = f2b(a), yh = f2b(yv);
            int sub = i & 3;
            if (sub == 0)      { px0 = ah;        py0 = yh; }
            else if (sub == 1) { px0 |= ah << 16; py0 |= yh << 16; }
            else if (sub == 2) { px1 = ah;        py1 = yh; }
            else {
                px1 |= ah << 16;  py1 |= yh << 16;
                int col = (c - 3) ^ swz;
                uint2 qx; qx.x = px0; qx.y = px1;
                uint2 qy; qy.x = py0; qy.y = py1;
                *(uint2*)(&sFt[0][w][col]) = qx;
                *(uint2*)(&sFt[1][w][col]) = qy;
            }
        }
    }
    __syncthreads();

    // ---- Phase A: sf[16][32] = wsb[16][256] @ [Xs;Y2] (rows 9..15 zero)
    {
        int lane = t & 63, wv = t >> 6;
        int l16 = lane & 15, half = lane >> 4, kk = half * 8;
        if (wv < 2) {
            int wA = wv * 16 + l16;
            int swzA = (wA & 7) << 3;
            f32x4 acc = (f32x4){0.f, 0.f, 0.f, 0.f};
#pragma unroll
            for (int ks = 0; ks < 8; ks++) {
                short8 av = *(const short8*)(wsb + l16 * 256 + ks * 32 + kk);
                int col = (((ks & 3) * 32 + kk)) ^ swzA;
                short8 bv = *(const short8*)(&sFt[ks >> 2][wA][0] + col);
                acc = __builtin_amdgcn_mfma_f32_16x16x32_bf16(av, bv, acc, 0, 0, 0);
            }
#pragma unroll
            for (int r = 0; r < 4; r++) {
                int tt = half * 4 + r;
                if (tt < KK) sSf[tt][wA] = acc[r];
            }
        }
    }
    __syncthreads();

    // ---- Phase B: dyn[c][w] = sum_taps X2patch * (cf[c][t] + sf[t][w])
    {
        float sfw[9];
#pragma unroll
        for (int q = 0; q < 9; q++) sfw[q] = sSf[q][w];
        unsigned int p0 = 0, p1 = 0;
#pragma unroll 4
        for (int i = 0; i < 16; i++) {
            int c = cg * 16 + i;
            const float* xp = xbase + (size_t)c * HWn;
            float tp[9];
            tp[0] = (hm && wm) ? xp[-Wn - 1] : 0.f;
            tp[1] = hm ? xp[-Wn] : 0.f;
            tp[2] = (hm && wp) ? xp[-Wn + 1] : 0.f;
            tp[3] = wm ? xp[-1] : 0.f;
            tp[4] = xp[0];
            tp[5] = wp ? xp[1] : 0.f;
            tp[6] = (hp && wm) ? xp[Wn - 1] : 0.f;
            tp[7] = hp ? xp[Wn] : 0.f;
            tp[8] = (hp && wp) ? xp[Wn + 1] : 0.f;
            const float* cfp = sCf + c * 9;
            float a = 0.f;
#pragma unroll
            for (int q = 0; q < 9; q++) a += tp[q] * (cfp[q] + sfw[q]);
            unsigned int ah = f2b(a);
            int sub = i & 3;
            if (sub == 0)      p0 = ah;
            else if (sub == 1) p0 |= ah << 16;
            else if (sub == 2) p1 = ah;
            else {
                p1 |= ah << 16;
                int col = (c - 3) ^ swz;
                uint2 q2; q2.x = p0; q2.y = p1;
                *(uint2*)(&sFt[1][w][col]) = q2;
            }
        }
    }
    __syncthreads();

    // ---- Phase C: out[o][w] = sum_k wf[o][k] * [Xs;dyn][k][w], K=256
    {
        int lane = t & 63, wv = t >> 6;
        int l16 = lane & 15, half = lane >> 4, kk = half * 8;
        f32x4 acc[2][2];
#pragma unroll
        for (int m = 0; m < 2; m++)
#pragma unroll
            for (int n = 0; n < 2; n++)
                acc[m][n] = (f32x4){0.f, 0.f, 0.f, 0.f};
#pragma unroll
        for (int ks = 0; ks < 8; ks++) {
            int bufi = ks >> 2;
            int kc = (ks & 3) * 32 + kk;
            short8 bfrag[2];
#pragma unroll
            for (int n = 0; n < 2; n++) {
                int wB = n * 16 + l16;
                int col = kc ^ ((wB & 7) << 3);
                bfrag[n] = *(const short8*)(&sFt[bufi][wB][0] + col);
            }
#pragma unroll
            for (int m = 0; m < 2; m++) {
                short8 av = *(const short8*)(
                    wfb + ((wv * 32 + m * 16 + l16) * 256 + ks * 32 + kk));
#pragma unroll
                for (int n = 0; n < 2; n++)
                    acc[m][n] = __builtin_amdgcn_mfma_f32_16x16x32_bf16(
                        av, bfrag[n], acc[m][n], 0, 0, 0);
            }
        }
        size_t obase = (size_t)b * Cn * HWn + (size_t)h * Wn + w0;
#pragma unroll
        for (int m = 0; m < 2; m++)
#pragma unroll
            for (int n = 0; n < 2; n++)
#pragma unroll
                for (int r = 0; r < 4; r++) {
                    int o = wv * 32 + m * 16 + half * 4 + r;
                    out[obase + (size_t)o * HWn + n * 16 + l16] = acc[m][n][r];
                }
    }
}

// ---------------------------------------------------------------------------
extern "C" void kernel_launch(void* const* d_in, const int* in_sizes, int n_in,
                              void* d_out, int out_size, void* d_ws, size_t ws_size,
                              hipStream_t stream) {
    (void)in_sizes; (void)n_in; (void)out_size; (void)ws_size;
    const float* X2  = (const float*)d_in[0];
    const float* Y2  = (const float*)d_in[1];
    const float* sw  = (const float*)d_in[2];
    const float* w1  = (const float*)d_in[3];
    const float* w2  = (const float*)d_in[4];
    const float* w3  = (const float*)d_in[5];
    const float* wsp = (const float*)d_in[6];
    const float* wf  = (const float*)d_in[7];
    float* out = (float*)d_out;

    float* wsf = (float*)d_ws;
    float* pws = wsf;                                      // 6144 f
    float* cf  = wsf + 6144;                               // 9216 f
    unsigned short* wfb = (unsigned short*)(wsf + 15360);  // 32768 u16
    unsigned short* wsb = (unsigned short*)(wsf + 31744);  // 4096 u16

    hipLaunchKernelGGL(k_pre, dim3(Bn * Cn), dim3(256), 0, stream, X2, Y2, pws);
    hipLaunchKernelGGL(k_ctx, dim3(Bn), dim3(256), 0, stream,
                       X2, pws, sw, w1, w2, w3, wf, wsp, cf, wfb, wsb);
    hipLaunchKernelGGL(k_main, dim3(Bn * Hn * 2), dim3(256), 0, stream,
                       X2, Y2, sw, wfb, wsb, cf, out);
}